// Round 4
// 950.047 us; speedup vs baseline: 1.0302x; 1.0302x over previous
//
#include <hip/hip_runtime.h>

typedef _Float16 half8 __attribute__((ext_vector_type(8)));
typedef _Float16 half4v __attribute__((ext_vector_type(4)));
typedef float f32x4 __attribute__((ext_vector_type(4)));

#define OUT_MAIN 33554432L   // B*S*H

// ws layout (bytes)
#define WS_PRE   0L          // pre_f16 (+bias folded): 67108864
#define WS_WIH   67108864L   // Wih f16: 2 MB
#define WS_WHH   69206016L   // Whh f16: 2 MB
#define WS_HBUF  71303168L   // h double buffer: 2*256*1024*2 = 1 MB
#define WS_BIAS  72351744L   // bias fp32: 4 KB
#define WS_CTR   72355840L   // 128 flags x 128 B = 16 KB
#define WS_XF16  72372224L   // optional x as f16: 67108864
#define WS_NEED_XF16 139481088UL

// Agent-scope relaxed atomics resolve at the Infinity Cache (memory-side,
// cross-XCD coherent). No fences -> no buffer_wbl2/buffer_inv.
__device__ __forceinline__ half8 ic_load16(const _Float16* p) {
  unsigned long long lo = __hip_atomic_load((unsigned long long*)p,
      __ATOMIC_RELAXED, __HIP_MEMORY_SCOPE_AGENT);
  unsigned long long hi = __hip_atomic_load((unsigned long long*)p + 1,
      __ATOMIC_RELAXED, __HIP_MEMORY_SCOPE_AGENT);
  union { unsigned long long u[2]; half8 h; } cv;
  cv.u[0] = lo; cv.u[1] = hi;
  return cv.h;
}

// ---------------------------------------------------------------------------
__global__ __launch_bounds__(256) void prep_kernel(
    const float* __restrict__ wih, const float* __restrict__ whh,
    const float* __restrict__ hid, const float* __restrict__ bih,
    const float* __restrict__ bhh, const float* __restrict__ x,
    _Float16* __restrict__ wihf, _Float16* __restrict__ whhf,
    _Float16* __restrict__ hbuf, float* __restrict__ bias,
    unsigned* __restrict__ ctr, _Float16* __restrict__ xf16, int do_x) {
  int tid = blockIdx.x * 256 + threadIdx.x;
  int np = gridDim.x * 256;
  for (int i = tid; i < 262144; i += np) {
    float4 v = ((const float4*)wih)[i];
    half4v h; h[0]=(_Float16)v.x; h[1]=(_Float16)v.y; h[2]=(_Float16)v.z; h[3]=(_Float16)v.w;
    ((half4v*)wihf)[i] = h;
  }
  for (int i = tid; i < 262144; i += np) {
    float4 v = ((const float4*)whh)[i];
    half4v h; h[0]=(_Float16)v.x; h[1]=(_Float16)v.y; h[2]=(_Float16)v.z; h[3]=(_Float16)v.w;
    ((half4v*)whhf)[i] = h;
  }
  for (int i = tid; i < 65536; i += np) {
    float4 v = ((const float4*)hid)[i];
    half4v h; h[0]=(_Float16)v.x; h[1]=(_Float16)v.y; h[2]=(_Float16)v.z; h[3]=(_Float16)v.w;
    ((half4v*)hbuf)[i] = h;
  }
  for (int i = tid; i < 1024; i += np) bias[i] = bih[i] + bhh[i];
  for (int i = tid; i < 4096; i += np) ctr[i] = 0u;
  if (do_x) {
    for (int i = tid; i < 8388608; i += np) {
      float4 v = ((const float4*)x)[i];
      half4v h; h[0]=(_Float16)v.x; h[1]=(_Float16)v.y; h[2]=(_Float16)v.z; h[3]=(_Float16)v.w;
      ((half4v*)xf16)[i] = h;
    }
  }
}

// ---------------------------------------------------------------------------
// gemm_pre (fallback, verified): A staged from fp32 x via register convert.
// ---------------------------------------------------------------------------
__global__ __launch_bounds__(256, 2) void gemm_pre(
    const float* __restrict__ x, const _Float16* __restrict__ wih,
    const float* __restrict__ bias, _Float16* __restrict__ pre) {
  __shared__ _Float16 Ash[128 * 64];
  __shared__ _Float16 Bsh[128 * 64];
  int tid = threadIdx.x;
  int lane = tid & 63, wid = tid >> 6;
  int l15 = lane & 15, quad = lane >> 4;
  int mt = blockIdx.x >> 3, nt = blockIdx.x & 7;
  int m0 = mt * 128, n0 = nt * 128;
  int wm = (wid >> 1) * 64, wn = (wid & 1) * 64;
  f32x4 acc[4][4] = {};

  for (int ko = 0; ko < 16; ++ko) {
    int k0 = ko * 64;
#pragma unroll
    for (int p = 0; p < 4; ++p) {
      int s = p * 256 + tid;
      int row = s >> 3;
      int kkh = (s & 7) ^ (row & 7);
      const float* g = x + (long)(m0 + row) * 1024 + k0 + kkh * 8;
      float4 v0 = ((const float4*)g)[0];
      float4 v1 = ((const float4*)g)[1];
      half8 hv;
      hv[0]=(_Float16)v0.x; hv[1]=(_Float16)v0.y; hv[2]=(_Float16)v0.z; hv[3]=(_Float16)v0.w;
      hv[4]=(_Float16)v1.x; hv[5]=(_Float16)v1.y; hv[6]=(_Float16)v1.z; hv[7]=(_Float16)v1.w;
      *(half8*)(Ash + (long)s * 8) = hv;
    }
#pragma unroll
    for (int p = 0; p < 4; ++p) {
      int s = p * 256 + tid;
      int row = s >> 3;
      int kkh = (s & 7) ^ (row & 7);
      const _Float16* g = wih + (long)(n0 + row) * 1024 + k0 + kkh * 8;
      __builtin_amdgcn_global_load_lds(
          (const __attribute__((address_space(1))) void*)g,
          (__attribute__((address_space(3))) void*)(Bsh + (p * 256 + wid * 64) * 8),
          16, 0, 0);
    }
    __syncthreads();
#pragma unroll
    for (int kk = 0; kk < 2; ++kk) {
      half8 af[4], bfr[4];
      int kkh = kk * 4 + quad;
#pragma unroll
      for (int i = 0; i < 4; ++i) {
        int ra = wm + i * 16 + l15;
        af[i] = *(const half8*)(Ash + (ra * 8 + (kkh ^ (ra & 7))) * 8);
        int rb = wn + i * 16 + l15;
        bfr[i] = *(const half8*)(Bsh + (rb * 8 + (kkh ^ (rb & 7))) * 8);
      }
#pragma unroll
      for (int i = 0; i < 4; ++i)
#pragma unroll
        for (int j = 0; j < 4; ++j)
          acc[i][j] = __builtin_amdgcn_mfma_f32_16x16x32_f16(af[i], bfr[j], acc[i][j], 0, 0, 0);
    }
    __syncthreads();
  }
#pragma unroll
  for (int i = 0; i < 4; ++i)
#pragma unroll
    for (int j = 0; j < 4; ++j) {
      int col = n0 + wn + j * 16 + l15;
      float bv = bias[col];
#pragma unroll
      for (int r = 0; r < 4; ++r) {
        int row = m0 + wm + i * 16 + quad * 4 + r;
        pre[(long)row * 1024 + col] = (_Float16)(acc[i][j][r] + bv);
      }
    }
}

// ---------------------------------------------------------------------------
// gemm_pre_f16: A comes pre-converted (xf16) and is staged via the same
// verified pre-swizzled global_load_lds pattern as B — no VALU convert in
// the hot loop. No inter-block synchronization anywhere.
// ---------------------------------------------------------------------------
__global__ __launch_bounds__(256, 2) void gemm_pre_f16(
    const _Float16* __restrict__ xf, const _Float16* __restrict__ wih,
    const float* __restrict__ bias, _Float16* __restrict__ pre) {
  __shared__ _Float16 Ash[128 * 64];
  __shared__ _Float16 Bsh[128 * 64];
  int tid = threadIdx.x;
  int lane = tid & 63, wid = tid >> 6;
  int l15 = lane & 15, quad = lane >> 4;
  int mt = blockIdx.x >> 3, nt = blockIdx.x & 7;
  int m0 = mt * 128, n0 = nt * 128;
  int wm = (wid >> 1) * 64, wn = (wid & 1) * 64;
  f32x4 acc[4][4] = {};

  for (int ko = 0; ko < 16; ++ko) {
    int k0 = ko * 64;
#pragma unroll
    for (int p = 0; p < 4; ++p) {
      int s = p * 256 + tid;
      int row = s >> 3;
      int kkh = (s & 7) ^ (row & 7);
      const _Float16* ga = xf + (long)(m0 + row) * 1024 + k0 + kkh * 8;
      __builtin_amdgcn_global_load_lds(
          (const __attribute__((address_space(1))) void*)ga,
          (__attribute__((address_space(3))) void*)(Ash + (p * 256 + wid * 64) * 8),
          16, 0, 0);
      const _Float16* gb = wih + (long)(n0 + row) * 1024 + k0 + kkh * 8;
      __builtin_amdgcn_global_load_lds(
          (const __attribute__((address_space(1))) void*)gb,
          (__attribute__((address_space(3))) void*)(Bsh + (p * 256 + wid * 64) * 8),
          16, 0, 0);
    }
    __syncthreads();
#pragma unroll
    for (int kk = 0; kk < 2; ++kk) {
      half8 af[4], bfr[4];
      int kkh = kk * 4 + quad;
#pragma unroll
      for (int i = 0; i < 4; ++i) {
        int ra = wm + i * 16 + l15;
        af[i] = *(const half8*)(Ash + (ra * 8 + (kkh ^ (ra & 7))) * 8);
        int rb = wn + i * 16 + l15;
        bfr[i] = *(const half8*)(Bsh + (rb * 8 + (kkh ^ (rb & 7))) * 8);
      }
#pragma unroll
      for (int i = 0; i < 4; ++i)
#pragma unroll
        for (int j = 0; j < 4; ++j)
          acc[i][j] = __builtin_amdgcn_mfma_f32_16x16x32_f16(af[i], bfr[j], acc[i][j], 0, 0, 0);
    }
    __syncthreads();
  }
#pragma unroll
  for (int i = 0; i < 4; ++i)
#pragma unroll
    for (int j = 0; j < 4; ++j) {
      int col = n0 + wn + j * 16 + l15;
      float bv = bias[col];
#pragma unroll
      for (int r = 0; r < 4; ++r) {
        int row = m0 + wm + i * 16 + quad * 4 + r;
        pre[(long)row * 1024 + col] = (_Float16)(acc[i][j][r] + bv);
      }
    }
}

// ---------------------------------------------------------------------------
// rnn v3 (verified at 661 us): 128 blocks (rg 0..7 = blk&7, cg 0..15).
// Block: rows q0..q0+32, cols c0..c0+64. Waves split K (256 each). Weights
// 128 VGPR/wave, pinned. f32 partials in LDS (pad 36, conflict-free).
// Flag-array sync via agent-scope IC atomics, prefetch.
// ---------------------------------------------------------------------------
__global__ __launch_bounds__(256, 1) void rnn_kernel(
    const _Float16* __restrict__ pre, const _Float16* __restrict__ whhf,
    _Float16* __restrict__ hbuf, unsigned* ctr, float* __restrict__ out) {
  __shared__ float part[4][64][36];  // [kwave][col][row pad36] = 36 KB
  const int rg = blockIdx.x & 7, cg = blockIdx.x >> 3;
  const int tid = threadIdx.x;
  const int w = tid >> 6, lane = tid & 63;
  const int l15 = lane & 15, quad = lane >> 4;
  const int q0 = rg * 32, c0 = cg * 64;

  // Whh fragments: 64 cols x 256 K (quarter w) = 32 x half8 = 128 VGPR
  half8 bf[8][4];
#pragma unroll
  for (int kk = 0; kk < 8; ++kk)
#pragma unroll
    for (int j = 0; j < 4; ++j) {
      bf[kk][j] = *(const half8*)(whhf + (long)(c0 + j * 16 + l15) * 1024 +
                                  w * 256 + kk * 32 + quad * 8);
      asm volatile("" : "+v"(bf[kk][j]));  // pin: no remat/re-load in loop
    }

  // epilogue ownership: cols cA=tid&31, cB=cA+32; rows orow..orow+3
  const int cA = tid & 31, orow = (tid >> 5) * 4;
  long obA[4], obB[4];
  int hoA[4], hoB[4];
#pragma unroll
  for (int r = 0; r < 4; ++r) {
    int qg = q0 + orow + r;
    int b = qg & 63, ph = qg >> 6;
    obA[r] = (long)(b * 512 + ph) * 1024 + c0 + cA;
    obB[r] = obA[r] + 32;
    hoA[r] = qg * 1024 + c0 + cA;
    hoB[r] = hoA[r] + 32;
  }
  unsigned* flags = ctr + rg * 512;  // 16 flags, 128-B strided
  const int arow = q0 + l15;

  // prefetch pre for k=0
  _Float16 pvA[4], pvB[4];
#pragma unroll
  for (int r = 0; r < 4; ++r) { pvA[r] = pre[obA[r]]; pvB[r] = pre[obB[r]]; }

  for (int k = 0; k < 128; ++k) {
    const _Float16* hcur = hbuf + (long)(k & 1) * 262144;
    _Float16* hnxt = hbuf + (long)((k + 1) & 1) * 262144;
    // A fragments from IC (8 KB per wave per step)
    const _Float16* ap = hcur + (long)arow * 1024 + w * 256 + quad * 8;
    half8 a0[8], a1[8];
#pragma unroll
    for (int kk = 0; kk < 8; ++kk) {
      a0[kk] = ic_load16(ap + kk * 32);
      a1[kk] = ic_load16(ap + 16 * 1024 + kk * 32);
    }
    f32x4 acc[2][4] = {};
#pragma unroll
    for (int kk = 0; kk < 8; ++kk)
#pragma unroll
      for (int j = 0; j < 4; ++j) {
        acc[0][j] = __builtin_amdgcn_mfma_f32_16x16x32_f16(a0[kk], bf[kk][j], acc[0][j], 0, 0, 0);
        acc[1][j] = __builtin_amdgcn_mfma_f32_16x16x32_f16(a1[kk], bf[kk][j], acc[1][j], 0, 0, 0);
      }
#pragma unroll
    for (int t = 0; t < 2; ++t)
#pragma unroll
      for (int j = 0; j < 4; ++j)
        *(f32x4*)&part[w][j * 16 + l15][t * 16 + quad * 4] = acc[t][j];
    __syncthreads();
    // reduce 4 K-partials + pre, tanh
    float hA[4], hB[4];
    {
      f32x4 zA = {(float)pvA[0], (float)pvA[1], (float)pvA[2], (float)pvA[3]};
      f32x4 zB = {(float)pvB[0], (float)pvB[1], (float)pvB[2], (float)pvB[3]};
#pragma unroll
      for (int w4 = 0; w4 < 4; ++w4) {
        f32x4 pA = *(const f32x4*)&part[w4][cA][orow];
        f32x4 pB = *(const f32x4*)&part[w4][cA + 32][orow];
        zA += pA; zB += pB;
      }
#pragma unroll
      for (int r = 0; r < 4; ++r) {
        float eA = __expf(2.f * zA[r]);
        hA[r] = 1.f - 2.f * __builtin_amdgcn_rcpf(eA + 1.f);
        float eB = __expf(2.f * zB[r]);
        hB[r] = 1.f - 2.f * __builtin_amdgcn_rcpf(eB + 1.f);
      }
    }
    if (k < 127) {
      // h stores to IC first (they gate the flag)
#pragma unroll
      for (int r = 0; r < 4; ++r) {
        union { _Float16 h; unsigned short u; } ua, ub;
        ua.h = (_Float16)hA[r]; ub.h = (_Float16)hB[r];
        __hip_atomic_store((unsigned short*)(hnxt + hoA[r]), ua.u,
                           __ATOMIC_RELAXED, __HIP_MEMORY_SCOPE_AGENT);
        __hip_atomic_store((unsigned short*)(hnxt + hoB[r]), ub.u,
                           __ATOMIC_RELAXED, __HIP_MEMORY_SCOPE_AGENT);
      }
      __syncthreads();  // vmcnt(0) drain: h stores acked at IC
      if (tid == 0)
        __hip_atomic_store(&flags[cg * 32], (unsigned)(k + 1),
                           __ATOMIC_RELAXED, __HIP_MEMORY_SCOPE_AGENT);
      // off-chain work during the sync window: out stores + pre prefetch
#pragma unroll
      for (int r = 0; r < 4; ++r) {
        long ko = (long)k * 4096;
        out[obA[r] + ko] = hA[r];
        out[obB[r] + ko] = hB[r];
      }
#pragma unroll
      for (int r = 0; r < 4; ++r) {
        long ko = (long)(k + 1) * 4096;
        pvA[r] = pre[obA[r] + ko];
        pvB[r] = pre[obB[r] + ko];
      }
      // poll 16 flags with 16 lanes
      if (tid < 16) {
        while (__hip_atomic_load(&flags[tid * 32], __ATOMIC_RELAXED,
                                 __HIP_MEMORY_SCOPE_AGENT) < (unsigned)(k + 1))
          __builtin_amdgcn_s_sleep(1);
      }
      __syncthreads();
    } else {
#pragma unroll
      for (int r = 0; r < 4; ++r) {
        long ko = (long)k * 4096;
        out[obA[r] + ko] = hA[r];
        out[obB[r] + ko] = hB[r];
        out[OUT_MAIN + hoA[r]] = hA[r];
        out[OUT_MAIN + hoB[r]] = hB[r];
      }
    }
  }
}

// ---------------------------------------------------------------------------
extern "C" void kernel_launch(void* const* d_in, const int* in_sizes, int n_in,
                              void* d_out, int out_size, void* d_ws, size_t ws_size,
                              hipStream_t stream) {
  const float* x   = (const float*)d_in[0];
  const float* hid = (const float*)d_in[1];
  const float* wih = (const float*)d_in[2];
  const float* whh = (const float*)d_in[3];
  const float* bih = (const float*)d_in[4];
  const float* bhh = (const float*)d_in[5];
  char* ws = (char*)d_ws;
  _Float16* pre  = (_Float16*)(ws + WS_PRE);
  _Float16* wihf = (_Float16*)(ws + WS_WIH);
  _Float16* whhf = (_Float16*)(ws + WS_WHH);
  _Float16* hbuf = (_Float16*)(ws + WS_HBUF);
  float* bias    = (float*)(ws + WS_BIAS);
  unsigned* ctr  = (unsigned*)(ws + WS_CTR);
  _Float16* xf16 = (_Float16*)(ws + WS_XF16);
  float* out     = (float*)d_out;
  int big = (ws_size >= WS_NEED_XF16) ? 1 : 0;

  hipLaunchKernelGGL(prep_kernel, dim3(512), dim3(256), 0, stream,
                     wih, whh, hid, bih, bhh, x, wihf, whhf, hbuf, bias, ctr,
                     xf16, big);
  if (big)
    hipLaunchKernelGGL(gemm_pre_f16, dim3(2048), dim3(256), 0, stream,
                       xf16, wihf, bias, pre);
  else
    hipLaunchKernelGGL(gemm_pre, dim3(2048), dim3(256), 0, stream,
                       x, wihf, bias, pre);
  hipLaunchKernelGGL(rnn_kernel, dim3(128), dim3(256), 0, stream,
                     pre, whhf, hbuf, ctr, out);
}